// Round 1
// baseline (1549.867 us; speedup 1.0000x reference)
//
#include <hip/hip_runtime.h>
#include <math.h>

#define NN 27
#define HID 128
#define H2S 132          // padded row stride for H (breaks stride-128 bank aliasing)
#define SITERS 20

typedef float v4 __attribute__((ext_vector_type(4)));

// ---------------- Kernel 1: features + MLP + scores -> log_alpha (into d_out) ----------------
// block = 128 threads, one batch element per block.
__global__ __launch_bounds__(128) void k1_mlp(
    const float* __restrict__ A, const float* __restrict__ m,
    const float* __restrict__ tau_r,
    const float* __restrict__ ln1g, const float* __restrict__ ln1b,
    const float* __restrict__ W1, const float* __restrict__ b1,
    const float* __restrict__ W2, const float* __restrict__ b2,
    const float* __restrict__ ln2g, const float* __restrict__ ln2b,
    const float* __restrict__ protos, float* __restrict__ out)
{
    __shared__ __align__(16) float sH1[28 * HID];       // h1, row 27 zero-padded
    __shared__ __align__(16) float sH2[NN * H2S];       // raw h2, then normalized H; aliased for A at start
    __shared__ __align__(16) float sFeat[NN * 4 + 4];   // LN1(feat)
    __shared__ float sMu[NN], sRs[NN];

    const int b   = blockIdx.x;
    const int tid = threadIdx.x;
    const float* Ab = A + (size_t)b * (NN * NN);

    // ---- P0: stage A (729 floats) into sH2 region (dead until phase 3 stores) ----
    float* sA = sH2;
    for (int i = tid; i < NN * NN; i += 128) sA[i] = Ab[i];
    __syncthreads();

    // ---- P1: per-row features [log1p(rowsum), top1_offdiag, top2_offdiag, m], then LN1 ----
    if (tid < NN) {
        const int n = tid;
        float sum = 0.f, m1 = -1e30f, m2 = -1e30f;
        #pragma unroll
        for (int j = 0; j < NN; ++j) {
            float a = sA[n * NN + j];
            sum += a;
            float v = (j == n) ? 0.f : a;       // offdiag = A * (1 - eye)
            float nm1 = fmaxf(m1, v);
            m2 = fmaxf(m2, fminf(m1, v));
            m1 = nm1;
        }
        float f0 = log1pf(sum), f1 = m1, f2 = m2, f3 = m[(size_t)b * NN + n];
        float mu = 0.25f * (f0 + f1 + f2 + f3);
        float d0 = f0 - mu, d1 = f1 - mu, d2 = f2 - mu, d3 = f3 - mu;
        float var = 0.25f * (d0*d0 + d1*d1 + d2*d2 + d3*d3);
        float rs  = rsqrtf(var + 1e-5f);
        sFeat[n*4 + 0] = d0 * rs * ln1g[0] + ln1b[0];
        sFeat[n*4 + 1] = d1 * rs * ln1g[1] + ln1b[1];
        sFeat[n*4 + 2] = d2 * rs * ln1g[2] + ln1b[2];
        sFeat[n*4 + 3] = d3 * rs * ln1g[3] + ln1b[3];
    }
    sH1[27 * HID + tid] = 0.f;     // zero the pad row (read by the 4-row tiles)
    __syncthreads();

    // ---- P2: h1 = relu(featLN @ W1 + b1), thread t = column t ----
    {
        const int t = tid;
        const float w0 = W1[t], w1 = W1[HID + t], w2 = W1[2*HID + t], w3 = W1[3*HID + t];
        const float bb = b1[t];
        #pragma unroll 9
        for (int n = 0; n < NN; ++n) {
            v4 f = *(const v4*)&sFeat[n * 4];
            float v = fmaf(f[0], w0, fmaf(f[1], w1, fmaf(f[2], w2, fmaf(f[3], w3, bb))));
            sH1[n * HID + t] = fmaxf(v, 0.f);
        }
    }
    __syncthreads();

    // ---- P3: h2 = h1 @ W2 + b2. Register tile: 4 rows x 8 cols per thread. ----
    // thread -> (tcol 0..15 => 8 cols, g 0..7 => 4 rows; g==7 duplicates g==6, benign)
    const int tcol = tid & 15, g = tid >> 4;
    const int n0 = (g < 7 ? g : 6) * 4;
    const int t0 = tcol * 8;
    v4 acc[4][2];
    {
        v4 ba = *(const v4*)&b2[t0], bb2 = *(const v4*)&b2[t0 + 4];
        #pragma unroll
        for (int nn = 0; nn < 4; ++nn) { acc[nn][0] = ba; acc[nn][1] = bb2; }
        for (int k = 0; k < HID; k += 4) {
            v4 h[4];
            #pragma unroll
            for (int nn = 0; nn < 4; ++nn) h[nn] = *(const v4*)&sH1[(n0 + nn) * HID + k];
            #pragma unroll
            for (int kk = 0; kk < 4; ++kk) {
                const float* wr = &W2[(k + kk) * HID + t0];
                v4 wa = *(const v4*)wr;
                v4 wb = *(const v4*)(wr + 4);
                #pragma unroll
                for (int nn = 0; nn < 4; ++nn) {
                    float hv = h[nn][kk];
                    acc[nn][0] += hv * wa;
                    acc[nn][1] += hv * wb;
                }
            }
        }
    }
    // store raw h2 for LN stats
    #pragma unroll
    for (int nn = 0; nn < 4; ++nn) {
        int n = n0 + nn;
        if (n < NN) {
            *(v4*)&sH2[n * H2S + t0]     = acc[nn][0];
            *(v4*)&sH2[n * H2S + t0 + 4] = acc[nn][1];
        }
    }
    __syncthreads();

    // ---- P4: LN2 stats per row ----
    if (tid < NN) {
        const float* row = &sH2[tid * H2S];
        float s = 0.f, ss = 0.f;
        #pragma unroll
        for (int q = 0; q < HID / 4; ++q) {
            v4 h = *(const v4*)&row[q * 4];
            s  += h[0] + h[1] + h[2] + h[3];
            ss += h[0]*h[0] + h[1]*h[1] + h[2]*h[2] + h[3]*h[3];
        }
        float mu  = s * (1.0f / HID);
        float var = ss * (1.0f / HID) - mu * mu;
        sMu[tid] = mu;
        sRs[tid] = rsqrtf(var + 1e-5f);
    }
    __syncthreads();

    // ---- P5a: write normalized H back from registers ----
    {
        v4 g2a = *(const v4*)&ln2g[t0], g2b = *(const v4*)&ln2g[t0 + 4];
        v4 ba2 = *(const v4*)&ln2b[t0], bb3 = *(const v4*)&ln2b[t0 + 4];
        #pragma unroll
        for (int nn = 0; nn < 4; ++nn) {
            int n = n0 + nn;
            if (n < NN) {
                float mu = sMu[n], rs = sRs[n];
                *(v4*)&sH2[n * H2S + t0]     = (acc[nn][0] - mu) * rs * g2a + ba2;
                *(v4*)&sH2[n * H2S + t0 + 4] = (acc[nn][1] - mu) * rs * g2b + bb3;
            }
        }
    }
    __syncthreads();

    // ---- P5b: log_alpha[i][j] = (H[j] . protos[i]) / tau, write to global ----
    // 126 threads: 14 i-groups (2 rows) x 9 j-groups (3 cols)
    const float inv_tau = 1.0f / tau_r[0];
    if (tid < 126) {
        const int ig = tid / 9, jg = tid - ig * 9;
        const int i0 = ig * 2, j0 = jg * 3;
        const int i1 = i0 + 1;
        const int i1c = (i1 < NN) ? i1 : (NN - 1);
        v4 va[2][3];
        #pragma unroll
        for (int ii = 0; ii < 2; ++ii)
            #pragma unroll
            for (int jj = 0; jj < 3; ++jj) va[ii][jj] = (v4)(0.f);
        for (int k = 0; k < HID; k += 4) {
            v4 hq0 = *(const v4*)&sH2[(j0 + 0) * H2S + k];
            v4 hq1 = *(const v4*)&sH2[(j0 + 1) * H2S + k];
            v4 hq2 = *(const v4*)&sH2[(j0 + 2) * H2S + k];
            v4 pa  = *(const v4*)&protos[i0  * HID + k];
            v4 pb  = *(const v4*)&protos[i1c * HID + k];
            va[0][0] += hq0 * pa; va[0][1] += hq1 * pa; va[0][2] += hq2 * pa;
            va[1][0] += hq0 * pb; va[1][1] += hq1 * pb; va[1][2] += hq2 * pb;
        }
        float* ob = out + (size_t)b * (NN * NN);
        #pragma unroll
        for (int ii = 0; ii < 2; ++ii) {
            int i = i0 + ii;
            if (i < NN) {
                #pragma unroll
                for (int jj = 0; jj < 3; ++jj) {
                    v4 t = va[ii][jj];
                    ob[i * NN + (j0 + jj)] = (t[0] + t[1] + t[2] + t[3]) * inv_tau;
                }
            }
        }
    }
}

// ---------------- Kernel 2: in-place log-domain Sinkhorn (20 iters) + exp ----------------
// block = 256 threads = 4 waves; 2 elements per wave (lanes 0..26 / 32..58), no __syncthreads.
__global__ __launch_bounds__(256) void k2_sinkhorn(float* __restrict__ la, int B)
{
    __shared__ __align__(16) float sLa[8 * 768];   // 8 elements, 27 rows of stride 28, elt stride 768

    const int w = threadIdx.x >> 6;
    const int l = threadIdx.x & 63;
    const int half = l >> 5, r = l & 31;
    const int eb = blockIdx.x * 8 + w * 2;
    if (eb >= B) return;
    const int nel = (B - eb >= 2) ? 2 : 1;

    float* sw = sLa + (w * 2) * 768;
    const size_t gbase = (size_t)eb * (NN * NN);

    // wave-local load, 27-stride -> 28-stride
    for (int idx = l; idx < nel * NN * NN; idx += 64) {
        int e = (idx >= NN * NN) ? 1 : 0;
        int p = idx - e * (NN * NN);
        int row = p / NN, col = p - row * NN;
        sw[e * 768 + row * 28 + col] = la[gbase + idx];
    }
    __builtin_amdgcn_wave_barrier();

    float* se = sw + half * 768;
    const bool act = (r < NN) && (half < nel);

    for (int it = 0; it < SITERS; ++it) {
        // row normalize (over j): lane r owns row r, contiguous
        if (act) {
            float* rp = se + r * 28;
            v4 q[7];
            #pragma unroll
            for (int qi = 0; qi < 7; ++qi) q[qi] = *(const v4*)&rp[qi * 4];
            float s = 0.f;
            #pragma unroll
            for (int qi = 0; qi < 6; ++qi)
                s += __expf(q[qi][0]) + __expf(q[qi][1]) + __expf(q[qi][2]) + __expf(q[qi][3]);
            s += __expf(q[6][0]) + __expf(q[6][1]) + __expf(q[6][2]);
            float L = __logf(s);
            #pragma unroll
            for (int qi = 0; qi < 7; ++qi) { q[qi] -= L; *(v4*)&rp[qi * 4] = q[qi]; }
        }
        __builtin_amdgcn_wave_barrier();
        // col normalize (over i): lane r owns column r, stride 28
        if (act) {
            float* cp = se + r;
            float x[NN];
            float s = 0.f;
            #pragma unroll
            for (int i = 0; i < NN; ++i) { x[i] = cp[i * 28]; s += __expf(x[i]); }
            float L = __logf(s);
            #pragma unroll
            for (int i = 0; i < NN; ++i) cp[i * 28] = x[i] - L;
        }
        __builtin_amdgcn_wave_barrier();
    }

    // wave-local exp + store back, coalesced
    for (int idx = l; idx < nel * NN * NN; idx += 64) {
        int e = (idx >= NN * NN) ? 1 : 0;
        int p = idx - e * (NN * NN);
        int row = p / NN, col = p - row * NN;
        la[gbase + idx] = __expf(sw[e * 768 + row * 28 + col]);
    }
}

extern "C" void kernel_launch(void* const* d_in, const int* in_sizes, int n_in,
                              void* d_out, int out_size, void* d_ws, size_t ws_size,
                              hipStream_t stream) {
    const float* A      = (const float*)d_in[0];
    const float* m      = (const float*)d_in[1];
    const float* tau_r  = (const float*)d_in[2];
    const float* ln1g   = (const float*)d_in[3];
    const float* ln1b   = (const float*)d_in[4];
    const float* W1     = (const float*)d_in[5];
    const float* b1     = (const float*)d_in[6];
    const float* W2     = (const float*)d_in[7];
    const float* b2     = (const float*)d_in[8];
    const float* ln2g   = (const float*)d_in[9];
    const float* ln2b   = (const float*)d_in[10];
    const float* protos = (const float*)d_in[11];
    float* out = (float*)d_out;

    const int B = in_sizes[0] / (NN * NN);

    k1_mlp<<<B, 128, 0, stream>>>(A, m, tau_r, ln1g, ln1b, W1, b1, W2, b2,
                                  ln2g, ln2b, protos, out);
    const int blocks2 = (B + 7) / 8;
    k2_sinkhorn<<<blocks2, 256, 0, stream>>>(out, B);
}